// Round 7
// baseline (405.687 us; speedup 1.0000x reference)
//
#include <hip/hip_runtime.h>
#include <hip/hip_bf16.h>
#include <math.h>

#define NN 2048
#define DA 256
#define DK 64
#define DG 64
#define MR 8          // rows per block
#define TPB 512       // 8 waves

typedef float f32x4 __attribute__((ext_vector_type(4)));

__device__ __forceinline__ float wave_reduce_max(float v) {
  #pragma unroll
  for (int o = 32; o >= 1; o >>= 1) v = fmaxf(v, __shfl_xor(v, o, 64));
  return v;
}
__device__ __forceinline__ float wave_reduce_sum(float v) {
  #pragma unroll
  for (int o = 32; o >= 1; o >>= 1) v += __shfl_xor(v, o, 64);
  return v;
}

// Allreduce-sum across each 16-lane group, pure VALU (DPP).
__device__ __forceinline__ float dpp_reduce16(float x) {
  int t;
  t = __builtin_amdgcn_update_dpp(0, __float_as_int(x), 0xB1, 0xF, 0xF, true);
  x += __int_as_float(t);
  t = __builtin_amdgcn_update_dpp(0, __float_as_int(x), 0x4E, 0xF, 0xF, true);
  x += __int_as_float(t);
  t = __builtin_amdgcn_update_dpp(0, __float_as_int(x), 0x124, 0xF, 0xF, true);
  x += __int_as_float(t);
  t = __builtin_amdgcn_update_dpp(0, __float_as_int(x), 0x128, 0xF, 0xF, true);
  x += __int_as_float(t);
  return x;
}

__device__ __forceinline__ float dot4(const f32x4 a, const f32x4 b) {
  float d = a.x * b.x;
  d = fmaf(a.y, b.y, d);
  d = fmaf(a.z, b.z, d);
  d = fmaf(a.w, b.w, d);
  return d;
}

// One block per row m: stage f_a row in LDS, 192 threads each compute one
// output element of {w_k, w_q, w_v}.
__global__ __launch_bounds__(256) void proj_kernel(
    const float* __restrict__ fa,
    const float* __restrict__ WKw, const float* __restrict__ WKb,
    const float* __restrict__ WQw, const float* __restrict__ WQb,
    const float* __restrict__ WVw, const float* __restrict__ WVb,
    float* __restrict__ wk, float* __restrict__ wq, float* __restrict__ wv)
{
  __shared__ float s_fa[DA];
  const int m = blockIdx.x, tid = threadIdx.x;
  s_fa[tid] = fa[(size_t)m * DA + tid];
  __syncthreads();
  if (tid < 192) {
    const int o = tid >> 6, k = tid & 63;
    const float* W = (o == 0 ? WKw : (o == 1 ? WQw : WVw)) + (size_t)k * DA;
    const float* B = (o == 0 ? WKb : (o == 1 ? WQb : WVb));
    float acc = B[k];
    const float4* W4 = (const float4*)W;
    const float4* F4 = (const float4*)s_fa;
    #pragma unroll 8
    for (int c = 0; c < DA / 4; ++c) {
      float4 w4 = W4[c], f4 = F4[c];
      acc = fmaf(w4.x, f4.x, acc); acc = fmaf(w4.y, f4.y, acc);
      acc = fmaf(w4.z, f4.z, acc); acc = fmaf(w4.w, f4.w, acc);
    }
    float* dst = (o == 0 ? wk : (o == 1 ? wq : wv));
    dst[(size_t)m * DK + k] = acc;
  }
}

// One block (512 threads = 8 waves) per 8 output rows m0..m0+7.
// The block's pe region is 4MB CONTIGUOUS; the 8 waves walk it in flat
// address order together (wave w takes 1KB chunk it*8+w) -> 256 fat
// sequential HBM streams instead of 2048 interleaved ones.
__global__ __launch_bounds__(512) void fused_kernel(
    const float* __restrict__ pe,
    const float* __restrict__ wgw, const float* __restrict__ wgb,
    const float* __restrict__ wk, const float* __restrict__ wq,
    const float* __restrict__ wv,
    float* __restrict__ out)
{
  __shared__ float s_sc[MR][NN];        // 64 KB: scores -> logits -> probs
  __shared__ float s_pacc[8][MR][DK];   // 16 KB partials
  __shared__ float s_rsum[MR];

  const int m0 = blockIdx.x * MR;
  const int tid = threadIdx.x;
  const int wave = tid >> 6, lane = tid & 63;
  const int sub = lane >> 4;            // n within a 4-n chunk
  const int c4  = lane & 15;            // float4 chunk within 64 floats

  // ---- pre-phase: s_sc[i][n] = 0.125 * (wk[m0+i] . wq[n]) ----
  {
    float acc[NN / TPB][MR];            // 4 x 8
    #pragma unroll
    for (int j = 0; j < NN / TPB; ++j)
      #pragma unroll
      for (int i = 0; i < MR; ++i) acc[j][i] = 0.f;
    #pragma unroll 4
    for (int c = 0; c < DK / 4; ++c) {
      f32x4 wkc[MR];
      #pragma unroll
      for (int i = 0; i < MR; ++i)
        wkc[i] = ((const f32x4*)(wk + (size_t)(m0 + i) * DK))[c];
      #pragma unroll
      for (int j = 0; j < NN / TPB; ++j) {
        const int n = j * TPB + tid;
        const f32x4 q = ((const f32x4*)(wq + (size_t)n * DK))[c];
        #pragma unroll
        for (int i = 0; i < MR; ++i) {
          acc[j][i] = fmaf(q.x, wkc[i].x, acc[j][i]);
          acc[j][i] = fmaf(q.y, wkc[i].y, acc[j][i]);
          acc[j][i] = fmaf(q.z, wkc[i].z, acc[j][i]);
          acc[j][i] = fmaf(q.w, wkc[i].w, acc[j][i]);
        }
      }
    }
    #pragma unroll
    for (int j = 0; j < NN / TPB; ++j) {
      const int n = j * TPB + tid;
      #pragma unroll
      for (int i = 0; i < MR; ++i)
        s_sc[i][n] = acc[j][i] * 0.125f;
    }
  }
  __syncthreads();

  // ---- phase 1: geometric term, one flat 4MB stream per block ----
  const f32x4 wg4 = ((const f32x4*)wgw)[c4];
  const float gb = wgb[0];
  const f32x4* peb = (const f32x4*)(pe + (size_t)m0 * NN * DG);
  #pragma unroll 4
  for (int it = 0; it < (MR * NN / 4) / 8; ++it) {   // 512 iters
    const int ch = it * 8 + wave;        // 1KB chunk index within 4MB region
    const f32x4 p = __builtin_nontemporal_load(peb + (size_t)ch * 64 + lane);
    const int i  = ch >> 9;              // row = ch / (NN/4)
    const int nb = (ch & 511) * 4;       // first n of this chunk
    float dg = dot4(p, wg4);
    dg = dpp_reduce16(dg);
    if (c4 == 0) {
      // relu -> clip(1e-6) -> log  ==  log(max(x, 1e-6))
      s_sc[i][nb + sub] += __logf(fmaxf(dg + gb, 1e-6f));
    }
  }
  __syncthreads();

  // ---- phase 2: per-row softmax, wave w owns row w ----
  {
    float mx = -INFINITY;
    #pragma unroll
    for (int j = 0; j < NN / 64; ++j)
      mx = fmaxf(mx, s_sc[wave][j * 64 + lane]);
    mx = wave_reduce_max(mx);
    float sm = 0.f;
    #pragma unroll
    for (int j = 0; j < NN / 64; ++j) {
      const float pr = __expf(s_sc[wave][j * 64 + lane] - mx);
      s_sc[wave][j * 64 + lane] = pr;
      sm += pr;
    }
    sm = wave_reduce_sum(sm);
    if (lane == 0) s_rsum[wave] = sm;
  }
  __syncthreads();

  // ---- phase 3: out = probs @ wv; wave w owns n-range, 8 rows each ----
  f32x4 vacc[MR];
  #pragma unroll
  for (int i = 0; i < MR; ++i) vacc[i] = (f32x4){0.f, 0.f, 0.f, 0.f};
  const int nbase = wave * (NN / 8);
  #pragma unroll 4
  for (int it = 0; it < (NN / 8) / 4; ++it) {        // 64 iters
    const int n = nbase + it * 4 + sub;
    const f32x4 v = ((const f32x4*)(wv + (size_t)n * DK))[c4];
    #pragma unroll
    for (int i = 0; i < MR; ++i) {
      const float pr = s_sc[i][n];
      vacc[i].x = fmaf(pr, v.x, vacc[i].x);
      vacc[i].y = fmaf(pr, v.y, vacc[i].y);
      vacc[i].z = fmaf(pr, v.z, vacc[i].z);
      vacc[i].w = fmaf(pr, v.w, vacc[i].w);
    }
  }
  #pragma unroll
  for (int i = 0; i < MR; ++i) {
    vacc[i].x += __shfl_xor(vacc[i].x, 16, 64); vacc[i].x += __shfl_xor(vacc[i].x, 32, 64);
    vacc[i].y += __shfl_xor(vacc[i].y, 16, 64); vacc[i].y += __shfl_xor(vacc[i].y, 32, 64);
    vacc[i].z += __shfl_xor(vacc[i].z, 16, 64); vacc[i].z += __shfl_xor(vacc[i].z, 32, 64);
    vacc[i].w += __shfl_xor(vacc[i].w, 16, 64); vacc[i].w += __shfl_xor(vacc[i].w, 32, 64);
  }
  if (lane < 16) {
    #pragma unroll
    for (int i = 0; i < MR; ++i)
      ((f32x4*)s_pacc[wave][i])[c4] = vacc[i];
  }
  __syncthreads();
  {
    const int i = tid >> 6, k = tid & 63;   // 512 threads = 8 rows x 64 dims
    float r = 0.f;
    #pragma unroll
    for (int w = 0; w < 8; ++w) r += s_pacc[w][i][k];
    out[(size_t)(m0 + i) * DK + k] = r / s_rsum[i];
  }
}

extern "C" void kernel_launch(void* const* d_in, const int* in_sizes, int n_in,
                              void* d_out, int out_size, void* d_ws, size_t ws_size,
                              hipStream_t stream) {
  const float* fa  = (const float*)d_in[0];
  const float* pe  = (const float*)d_in[1];
  const float* wgw = (const float*)d_in[2];
  const float* wgb = (const float*)d_in[3];
  const float* wkw = (const float*)d_in[4];
  const float* wkb = (const float*)d_in[5];
  const float* wqw = (const float*)d_in[6];
  const float* wqb = (const float*)d_in[7];
  const float* wvw = (const float*)d_in[8];
  const float* wvb = (const float*)d_in[9];
  float* out = (float*)d_out;

  float* wk = (float*)d_ws;          // [NN, DK]
  float* wq = wk + (size_t)NN * DK;  // [NN, DK]
  float* wv = wq + (size_t)NN * DK;  // [NN, DK]

  proj_kernel<<<NN, 256, 0, stream>>>(fa, wkw, wkb, wqw, wqb, wvw, wvb, wk, wq, wv);
  fused_kernel<<<NN / MR, TPB, 0, stream>>>(pe, wgw, wgb, wk, wq, wv, out);
}

// Round 8
// 345.452 us; speedup vs baseline: 1.1744x; 1.1744x over previous
//
#include <hip/hip_runtime.h>
#include <hip/hip_bf16.h>
#include <math.h>

#define NN 2048
#define DA 256
#define DK 64
#define DG 64

typedef float f32x4 __attribute__((ext_vector_type(4)));

__device__ __forceinline__ float wave_reduce_max(float v) {
  #pragma unroll
  for (int o = 32; o >= 1; o >>= 1) v = fmaxf(v, __shfl_xor(v, o, 64));
  return v;
}
__device__ __forceinline__ float wave_reduce_sum(float v) {
  #pragma unroll
  for (int o = 32; o >= 1; o >>= 1) v += __shfl_xor(v, o, 64);
  return v;
}

// Allreduce-sum across each 16-lane group, pure VALU (DPP).
__device__ __forceinline__ float dpp_reduce16(float x) {
  int t;
  t = __builtin_amdgcn_update_dpp(0, __float_as_int(x), 0xB1, 0xF, 0xF, true);
  x += __int_as_float(t);
  t = __builtin_amdgcn_update_dpp(0, __float_as_int(x), 0x4E, 0xF, 0xF, true);
  x += __int_as_float(t);
  t = __builtin_amdgcn_update_dpp(0, __float_as_int(x), 0x124, 0xF, 0xF, true);
  x += __int_as_float(t);
  t = __builtin_amdgcn_update_dpp(0, __float_as_int(x), 0x128, 0xF, 0xF, true);
  x += __int_as_float(t);
  return x;
}

__device__ __forceinline__ float dot4(const f32x4 a, const f32x4 b) {
  float d = a.x * b.x;
  d = fmaf(a.y, b.y, d);
  d = fmaf(a.z, b.z, d);
  d = fmaf(a.w, b.w, d);
  return d;
}

// One block per row m: stage f_a row in LDS, 192 threads each compute one
// output element of {w_k, w_q, w_v}.
__global__ __launch_bounds__(256) void proj_kernel(
    const float* __restrict__ fa,
    const float* __restrict__ WKw, const float* __restrict__ WKb,
    const float* __restrict__ WQw, const float* __restrict__ WQb,
    const float* __restrict__ WVw, const float* __restrict__ WVb,
    float* __restrict__ wk, float* __restrict__ wq, float* __restrict__ wv)
{
  __shared__ float s_fa[DA];
  const int m = blockIdx.x, tid = threadIdx.x;
  s_fa[tid] = fa[(size_t)m * DA + tid];
  __syncthreads();
  if (tid < 192) {
    const int o = tid >> 6, k = tid & 63;
    const float* W = (o == 0 ? WKw : (o == 1 ? WQw : WVw)) + (size_t)k * DA;
    const float* B = (o == 0 ? WKb : (o == 1 ? WQb : WVb));
    float acc = B[k];
    const float4* W4 = (const float4*)W;
    const float4* F4 = (const float4*)s_fa;
    #pragma unroll 8
    for (int c = 0; c < DA / 4; ++c) {
      float4 w4 = W4[c], f4 = F4[c];
      acc = fmaf(w4.x, f4.x, acc); acc = fmaf(w4.y, f4.y, acc);
      acc = fmaf(w4.z, f4.z, acc); acc = fmaf(w4.w, f4.w, acc);
    }
    float* dst = (o == 0 ? wk : (o == 1 ? wq : wv));
    dst[(size_t)m * DK + k] = acc;
  }
}

// S[m][n] = 0.125 * (wk[m] . wq[n]); block = 4 m-rows x all n.
__global__ __launch_bounds__(256) void scores_kernel(
    const float* __restrict__ wk, const float* __restrict__ wq,
    float* __restrict__ S)
{
  const int m0 = blockIdx.x * 4;
  const int tid = threadIdx.x;
  float acc[8][4];
  #pragma unroll
  for (int j = 0; j < 8; ++j)
    #pragma unroll
    for (int i = 0; i < 4; ++i) acc[j][i] = 0.f;
  #pragma unroll 4
  for (int c = 0; c < DK / 4; ++c) {
    f32x4 wkc[4];
    #pragma unroll
    for (int i = 0; i < 4; ++i)
      wkc[i] = ((const f32x4*)(wk + (size_t)(m0 + i) * DK))[c];
    #pragma unroll
    for (int j = 0; j < 8; ++j) {
      const int n = j * 256 + tid;
      const f32x4 q = ((const f32x4*)(wq + (size_t)n * DK))[c];
      #pragma unroll
      for (int i = 0; i < 4; ++i) {
        acc[j][i] = fmaf(q.x, wkc[i].x, acc[j][i]);
        acc[j][i] = fmaf(q.y, wkc[i].y, acc[j][i]);
        acc[j][i] = fmaf(q.z, wkc[i].z, acc[j][i]);
        acc[j][i] = fmaf(q.w, wkc[i].w, acc[j][i]);
      }
    }
  }
  #pragma unroll
  for (int j = 0; j < 8; ++j) {
    const int n = j * 256 + tid;
    #pragma unroll
    for (int i = 0; i < 4; ++i)
      S[(size_t)(m0 + i) * NN + n] = acc[j][i] * 0.125f;
  }
}

// One block (256 threads = 4 waves) per output row m.
// Preload S-row into LDS; hot loop = single NT pe load + dot4 + dpp16 +
// masked log-add. Then standard block softmax + PV (R3 structure).
__global__ __launch_bounds__(256) void fused_kernel(
    const float* __restrict__ pe,
    const float* __restrict__ wgw, const float* __restrict__ wgb,
    const float* __restrict__ S, const float* __restrict__ wv,
    float* __restrict__ out)
{
  __shared__ float s_logit[NN];          // 8 KB: scores -> logits -> probs
  __shared__ float s_rmax[4], s_rsum[4];
  __shared__ float s_pacc[4][4][DK];     // 4 KB partials

  const int m = blockIdx.x, tid = threadIdx.x;
  const int wave = tid >> 6, lane = tid & 63;
  const int sub = lane >> 4;             // n within a 4-n chunk
  const int c4  = lane & 15;             // float4 chunk within 64 floats

  // preload S row (coalesced f32x4)
  {
    const f32x4* Sr = (const f32x4*)(S + (size_t)m * NN);
    f32x4* L = (f32x4*)s_logit;
    #pragma unroll
    for (int j = 0; j < (NN / 4) / 256; ++j)     // 2 iters
      L[j * 256 + tid] = Sr[j * 256 + tid];
  }
  const f32x4 wg4 = ((const f32x4*)wgw)[c4];
  const float gb = wgb[0];
  __syncthreads();

  // ---- phase 1: geometric log-term, single-stream ----
  const int n0 = wave * (NN / 4);
  #pragma unroll 4
  for (int it = 0; it < (NN / 4) / 4; ++it) {    // 128 iters, 4 n's each
    const int nb = n0 + it * 4;
    const f32x4 p = __builtin_nontemporal_load(
        (const f32x4*)(pe + ((size_t)m * NN + nb) * DG) + lane);
    float dg = dot4(p, wg4);
    dg = dpp_reduce16(dg);
    if (c4 == 0) {
      // relu -> clip(1e-6) -> log  ==  log(max(x, 1e-6))
      s_logit[nb + sub] += __logf(fmaxf(dg + gb, 1e-6f));
    }
  }
  __syncthreads();

  // ---- phase 2: max, exp, sum ----
  float mx = -INFINITY;
  #pragma unroll
  for (int i = 0; i < NN / 256; ++i)
    mx = fmaxf(mx, s_logit[i * 256 + tid]);
  mx = wave_reduce_max(mx);
  if (lane == 0) s_rmax[wave] = mx;
  __syncthreads();
  const float rmax = fmaxf(fmaxf(s_rmax[0], s_rmax[1]), fmaxf(s_rmax[2], s_rmax[3]));
  float lsum = 0.f;
  #pragma unroll
  for (int i = 0; i < NN / 256; ++i) {
    const int n = i * 256 + tid;
    const float p = __expf(s_logit[n] - rmax);
    s_logit[n] = p;
    lsum += p;
  }
  lsum = wave_reduce_sum(lsum);
  if (lane == 0) s_rsum[wave] = lsum;
  __syncthreads();
  const float inv = 1.0f / (s_rsum[0] + s_rsum[1] + s_rsum[2] + s_rsum[3]);

  // ---- phase 3: out[m,:] = p-row @ w_v, float4 loads ----
  f32x4 acc = {0.f, 0.f, 0.f, 0.f};
  #pragma unroll 8
  for (int it = 0; it < (NN / 4) / 4; ++it) {
    const int nb = n0 + it * 4;
    const float pb = s_logit[nb + sub];
    const f32x4 v = ((const f32x4*)(wv + (size_t)(nb + sub) * DK))[c4];
    acc.x = fmaf(pb, v.x, acc.x);
    acc.y = fmaf(pb, v.y, acc.y);
    acc.z = fmaf(pb, v.z, acc.z);
    acc.w = fmaf(pb, v.w, acc.w);
  }
  ((f32x4*)&s_pacc[wave][sub][0])[c4] = acc;
  __syncthreads();
  if (tid < DK) {
    float r = 0.f;
    #pragma unroll
    for (int w = 0; w < 4; ++w)
      #pragma unroll
      for (int s = 0; s < 4; ++s)
        r += s_pacc[w][s][tid];
    out[(size_t)m * DK + tid] = r * inv;
  }
}

extern "C" void kernel_launch(void* const* d_in, const int* in_sizes, int n_in,
                              void* d_out, int out_size, void* d_ws, size_t ws_size,
                              hipStream_t stream) {
  const float* fa  = (const float*)d_in[0];
  const float* pe  = (const float*)d_in[1];
  const float* wgw = (const float*)d_in[2];
  const float* wgb = (const float*)d_in[3];
  const float* wkw = (const float*)d_in[4];
  const float* wkb = (const float*)d_in[5];
  const float* wqw = (const float*)d_in[6];
  const float* wqb = (const float*)d_in[7];
  const float* wvw = (const float*)d_in[8];
  const float* wvb = (const float*)d_in[9];
  float* out = (float*)d_out;

  float* wk = (float*)d_ws;          // [NN, DK]
  float* wq = wk + (size_t)NN * DK;  // [NN, DK]
  float* wv = wq + (size_t)NN * DK;  // [NN, DK]
  float* S  = wv + (size_t)NN * DK;  // [NN, NN]  (16.8 MB)

  proj_kernel<<<NN, 256, 0, stream>>>(fa, wkw, wkb, wqw, wqb, wvw, wvb, wk, wq, wv);
  scores_kernel<<<NN / 4, 256, 0, stream>>>(wk, wq, S);
  fused_kernel<<<NN, 256, 0, stream>>>(pe, wgw, wgb, S, wv, out);
}

// Round 9
// 279.175 us; speedup vs baseline: 1.4532x; 1.2374x over previous
//
#include <hip/hip_runtime.h>
#include <hip/hip_bf16.h>
#include <math.h>

#define NN 2048
#define DA 256
#define DK 64
#define DG 64

typedef float f32x4 __attribute__((ext_vector_type(4)));

__device__ __forceinline__ float wave_reduce_max(float v) {
  #pragma unroll
  for (int o = 32; o >= 1; o >>= 1) v = fmaxf(v, __shfl_xor(v, o, 64));
  return v;
}
__device__ __forceinline__ float wave_reduce_sum(float v) {
  #pragma unroll
  for (int o = 32; o >= 1; o >>= 1) v += __shfl_xor(v, o, 64);
  return v;
}

// Allreduce-sum across each 16-lane group, pure VALU (DPP), no LDS pipe.
__device__ __forceinline__ float dpp_reduce16(float x) {
  int t;
  t = __builtin_amdgcn_update_dpp(0, __float_as_int(x), 0xB1, 0xF, 0xF, true);
  x += __int_as_float(t);
  t = __builtin_amdgcn_update_dpp(0, __float_as_int(x), 0x4E, 0xF, 0xF, true);
  x += __int_as_float(t);
  t = __builtin_amdgcn_update_dpp(0, __float_as_int(x), 0x124, 0xF, 0xF, true);
  x += __int_as_float(t);
  t = __builtin_amdgcn_update_dpp(0, __float_as_int(x), 0x128, 0xF, 0xF, true);
  x += __int_as_float(t);
  return x;
}

__device__ __forceinline__ float dot4(const f32x4 a, const f32x4 b) {
  float d = a.x * b.x;
  d = fmaf(a.y, b.y, d);
  d = fmaf(a.z, b.z, d);
  d = fmaf(a.w, b.w, d);
  return d;
}

// One block per row m: stage f_a row in LDS, 192 threads each compute one
// output element of {w_k, w_q, w_v}.
__global__ __launch_bounds__(256) void proj_kernel(
    const float* __restrict__ fa,
    const float* __restrict__ WKw, const float* __restrict__ WKb,
    const float* __restrict__ WQw, const float* __restrict__ WQb,
    const float* __restrict__ WVw, const float* __restrict__ WVb,
    float* __restrict__ wk, float* __restrict__ wq, float* __restrict__ wv)
{
  __shared__ float s_fa[DA];
  const int m = blockIdx.x, tid = threadIdx.x;
  s_fa[tid] = fa[(size_t)m * DA + tid];
  __syncthreads();
  if (tid < 192) {
    const int o = tid >> 6, k = tid & 63;
    const float* W = (o == 0 ? WKw : (o == 1 ? WQw : WVw)) + (size_t)k * DA;
    const float* B = (o == 0 ? WKb : (o == 1 ? WQb : WVb));
    float acc = B[k];
    const float4* W4 = (const float4*)W;
    const float4* F4 = (const float4*)s_fa;
    #pragma unroll 8
    for (int c = 0; c < DA / 4; ++c) {
      float4 w4 = W4[c], f4 = F4[c];
      acc = fmaf(w4.x, f4.x, acc); acc = fmaf(w4.y, f4.y, acc);
      acc = fmaf(w4.z, f4.z, acc); acc = fmaf(w4.w, f4.w, acc);
    }
    float* dst = (o == 0 ? wk : (o == 1 ? wq : wv));
    dst[(size_t)m * DK + k] = acc;
  }
}

// One block (256 threads = 4 waves) per output row m.
// Phase 1: coalesced pe stream (PLAIN loads — the only change vs R3's 268us),
//          16 lanes per n, DPP allreduce.
// Phase 2: block softmax in LDS.
// Phase 3: float4 wv loads (lane = sub x c4), LDS-tile final combine.
__global__ __launch_bounds__(256) void fused_kernel(
    const float* __restrict__ pe,
    const float* __restrict__ wgw, const float* __restrict__ wgb,
    const float* __restrict__ wk, const float* __restrict__ wq,
    const float* __restrict__ wv,
    float* __restrict__ out)
{
  __shared__ float s_logit[NN];          // 8 KB: logits, then probs
  __shared__ float s_rmax[4], s_rsum[4];
  __shared__ float s_pacc[4][4][DK];     // 4 KB partial accumulators

  const int m = blockIdx.x, tid = threadIdx.x;
  const int wave = tid >> 6, lane = tid & 63;
  const int sub = lane >> 4;             // n within the 4-row chunk
  const int c4  = lane & 15;             // float4 chunk within 64 floats

  // loop-invariant per-lane slices
  const f32x4 wg4 = ((const f32x4*)wgw)[c4];
  const f32x4 wk4 = ((const f32x4*)(wk + (size_t)m * DK))[c4];
  const float gb = wgb[0];

  // ---- phase 1: logits, coalesced, plain loads ----
  float lmax = -INFINITY;
  const int n0 = wave * (NN / 4);
  #pragma unroll 4
  for (int it = 0; it < (NN / 4) / 4; ++it) {   // 128 iters, 4 n's each
    const int nb = n0 + it * 4;
    const f32x4 p = ((const f32x4*)(pe + ((size_t)m * NN + nb) * DG))[lane];
    const f32x4 q = ((const f32x4*)(wq + (size_t)nb * DK))[lane];
    float dg = dot4(p, wg4);
    float dq = dot4(q, wk4);
    dg = dpp_reduce16(dg);
    dq = dpp_reduce16(dq);
    if (c4 == 0) {
      // relu -> clip(1e-6) -> log  ==  log(max(x, 1e-6))
      const float logit = __logf(fmaxf(dg + gb, 1e-6f)) + dq * 0.125f;
      s_logit[nb + sub] = logit;
      lmax = fmaxf(lmax, logit);
    }
  }
  lmax = wave_reduce_max(lmax);
  if (lane == 0) s_rmax[wave] = lmax;
  __syncthreads();
  const float rmax = fmaxf(fmaxf(s_rmax[0], s_rmax[1]), fmaxf(s_rmax[2], s_rmax[3]));

  // ---- phase 2: exp + sum ----
  float lsum = 0.f;
  #pragma unroll
  for (int i = 0; i < NN / 256; ++i) {
    const int n = i * 256 + tid;
    const float p = __expf(s_logit[n] - rmax);
    s_logit[n] = p;
    lsum += p;
  }
  lsum = wave_reduce_sum(lsum);
  if (lane == 0) s_rsum[wave] = lsum;
  __syncthreads();
  const float inv = 1.0f / (s_rsum[0] + s_rsum[1] + s_rsum[2] + s_rsum[3]);

  // ---- phase 3: out[m,:] = p-row @ w_v, float4 loads ----
  f32x4 acc = {0.f, 0.f, 0.f, 0.f};
  #pragma unroll 4
  for (int it = 0; it < (NN / 4) / 4; ++it) {
    const int nb = n0 + it * 4;
    const float pb = s_logit[nb + sub];
    const f32x4 v = ((const f32x4*)(wv + (size_t)(nb + sub) * DK))[c4];
    acc.x = fmaf(pb, v.x, acc.x);
    acc.y = fmaf(pb, v.y, acc.y);
    acc.z = fmaf(pb, v.z, acc.z);
    acc.w = fmaf(pb, v.w, acc.w);
  }
  ((f32x4*)&s_pacc[wave][sub][0])[c4] = acc;
  __syncthreads();
  if (tid < DK) {
    float r = 0.f;
    #pragma unroll
    for (int w = 0; w < 4; ++w)
      #pragma unroll
      for (int s = 0; s < 4; ++s)
        r += s_pacc[w][s][tid];
    out[(size_t)m * DK + tid] = r * inv;
  }
}

extern "C" void kernel_launch(void* const* d_in, const int* in_sizes, int n_in,
                              void* d_out, int out_size, void* d_ws, size_t ws_size,
                              hipStream_t stream) {
  const float* fa  = (const float*)d_in[0];
  const float* pe  = (const float*)d_in[1];
  const float* wgw = (const float*)d_in[2];
  const float* wgb = (const float*)d_in[3];
  const float* wkw = (const float*)d_in[4];
  const float* wkb = (const float*)d_in[5];
  const float* wqw = (const float*)d_in[6];
  const float* wqb = (const float*)d_in[7];
  const float* wvw = (const float*)d_in[8];
  const float* wvb = (const float*)d_in[9];
  float* out = (float*)d_out;

  float* wk = (float*)d_ws;          // [NN, DK]
  float* wq = wk + (size_t)NN * DK;  // [NN, DK]
  float* wv = wq + (size_t)NN * DK;  // [NN, DK]

  proj_kernel<<<NN, 256, 0, stream>>>(fa, wkw, wkb, wqw, wqb, wvw, wvb, wk, wq, wv);
  fused_kernel<<<NN, 256, 0, stream>>>(pe, wgw, wgb, wk, wq, wv, out);
}